// Round 1
// baseline (253.329 us; speedup 1.0000x reference)
//
#include <hip/hip_runtime.h>
#include <hip/hip_bf16.h>
#include <math.h>

#define N_NODES 50000
#define N_EDGES 800000
#define FDIM 128
#define SCAN_BLOCKS 196   // ceil(50000/256)
#define XW_BLOCKS 391     // ceil(50000/128) row-tiles of 32 x 4 waves

typedef unsigned int uint32;
typedef __attribute__((ext_vector_type(8))) __bf16 bf16x8;
typedef __attribute__((ext_vector_type(8))) short short8;
typedef __attribute__((ext_vector_type(16))) float f32x16;

// part[] layout (ints): [0..195] raw block sums, [200..202] flags A/B/C,
//                       [256..451] scanned (exclusive) block offsets
#define FLAG_A 200
#define FLAG_B 201
#define FLAG_C 202
#define SCANNED 256

// round-to-nearest-even fp32 -> bf16 bits (finite inputs)
__device__ inline unsigned short f2bf(float f) {
  unsigned int u = __float_as_uint(f);
  unsigned int r = u + 0x7fffu + ((u >> 16) & 1u);
  return (unsigned short)(r >> 16);
}

// ---------------------------------------------------------------------------
// K1: GRU-evolve W (128x128) -> bf16 in MFMA frag-blocked layout
//     Wbf[((k>>3)*128 + n)*8 + (k&7)] = bf16(W[k][n])
//     + zero cnt/degf/flags (fused init).
// ---------------------------------------------------------------------------
__global__ __launch_bounds__(384) void evolve_kernel(
    const float* __restrict__ W0, const float* __restrict__ Wih,
    const float* __restrict__ Whh, const float* __restrict__ bih,
    const float* __restrict__ bhh, unsigned short* __restrict__ Wbf,
    int* __restrict__ cnt, float* __restrict__ degf, int* __restrict__ part) {
  int i = blockIdx.x;       // 0..127 (k row of W)
  int jj = threadIdx.x;     // 0..383
  // fused init: zero cnt/degf[0..N_NODES) and the three scan flags
  int gid = i * 384 + jj;   // 0..49151
  for (int j = gid; j < N_NODES; j += 128 * 384) {
    cnt[j] = 0;
    degf[j] = 0.0f;
  }
  if (gid < 3) part[FLAG_A + gid] = 0;  // FLAG_A/B/C contiguous

  __shared__ float w0s[FDIM];
  __shared__ float gis[3 * FDIM];
  __shared__ float ghs[3 * FDIM];
  if (jj < FDIM) w0s[jj] = W0[i * FDIM + jj];
  __syncthreads();
  float gi = bih[jj], gh = bhh[jj];
  const float4* wih4 = (const float4*)(Wih + jj * FDIM);
  const float4* whh4 = (const float4*)(Whh + jj * FDIM);
#pragma unroll 8
  for (int k = 0; k < FDIM / 4; k++) {
    float4 a = wih4[k];
    float4 b = whh4[k];
    float w0a = w0s[4 * k], w0b = w0s[4 * k + 1];
    float w0c = w0s[4 * k + 2], w0d = w0s[4 * k + 3];
    gi += a.x * w0a + a.y * w0b + a.z * w0c + a.w * w0d;
    gh += b.x * w0a + b.y * w0b + b.z * w0c + b.w * w0d;
  }
  gis[jj] = gi;
  ghs[jj] = gh;
  __syncthreads();
  if (jj < FDIM) {
    float r = 1.0f / (1.0f + expf(-(gis[jj] + ghs[jj])));
    float z = 1.0f / (1.0f + expf(-(gis[jj + FDIM] + ghs[jj + FDIM])));
    float nn = tanhf(gis[jj + 2 * FDIM] + r * ghs[jj + 2 * FDIM]);
    float val = (1.0f - z) * nn + z * w0s[jj];
    // frag-blocked bf16 store (k=i, n=jj)
    Wbf[((((i >> 3) << 7) + jj) << 3) + (i & 7)] = f2bf(val);
  }
}

// ---------------------------------------------------------------------------
// K2 (fused): blocks [0,XW_BLOCKS) run the MFMA GEMM y = bf16(x @ W);
// blocks [XW_BLOCKS, ...) run the rank histogram (1 int atomic/edge) and the
// weighted-degree accumulation (1 fire-and-forget float atomic/edge).
// xw blocks are FIRST so they launch immediately; hist blocks (atomic-latency
// bound, low pipe use) fill the remaining CUs concurrently.
// ---------------------------------------------------------------------------
__global__ __launch_bounds__(256) void histxw_kernel(
    const int* __restrict__ ei, const float* __restrict__ ew,
    int* __restrict__ cnt, float* __restrict__ degf, int* __restrict__ rank,
    const float* __restrict__ x, const unsigned short* __restrict__ Wbf,
    unsigned short* __restrict__ y, int n) {
  __shared__ short Bs[16 * 128 * 8];  // 32 KiB (xw path only)
  int t = threadIdx.x;
  if (blockIdx.x >= XW_BLOCKS) {
    // ---- hist + deg path ----
    int idx = (blockIdx.x - XW_BLOCKS) * 256 + t;
    if (idx < N_EDGES) {
      int dst = ei[N_EDGES + idx];
      rank[idx] = atomicAdd(&cnt[dst], 1);
      unsafeAtomicAdd(&degf[dst], ew[idx]);  // native global_atomic_add_f32
    }
    return;
  }
  // ---- xw path: one wave per 32-row tile, 32x32x16 bf16 MFMA ----
  // W is already bf16 in the exact Bs layout: linear 16B vector copy.
#pragma unroll
  for (int i = 0; i < 8; i++) {
    ((short8*)Bs)[i * 256 + t] = ((const short8*)Wbf)[i * 256 + t];
  }
  __syncthreads();

  int lane = t & 63;
  int wid = blockIdx.x * 4 + (t >> 6);
  int tr = wid * 32;  // tile row base
  if (tr >= n) return;
  int m = lane & 31;   // A row / D col within tile
  int q2 = lane >> 5;  // half-wave: k-offset selector

  int row = tr + m;
  if (row >= n) row = n - 1;  // tail clamp (stores are guarded)
  const float* xr = x + (size_t)row * FDIM;

  bf16x8 a[8];
#pragma unroll
  for (int kc = 0; kc < 8; kc++) {
    int k0 = kc * 16 + q2 * 8;
    float4 p = *(const float4*)(xr + k0);
    float4 q = *(const float4*)(xr + k0 + 4);
    short8 s;
    s[0] = (short)f2bf(p.x); s[1] = (short)f2bf(p.y);
    s[2] = (short)f2bf(p.z); s[3] = (short)f2bf(p.w);
    s[4] = (short)f2bf(q.x); s[5] = (short)f2bf(q.y);
    s[6] = (short)f2bf(q.z); s[7] = (short)f2bf(q.w);
    a[kc] = __builtin_bit_cast(bf16x8, s);
  }

  f32x16 acc[4];
#pragma unroll
  for (int ct = 0; ct < 4; ct++) {
#pragma unroll
    for (int r = 0; r < 16; r++) acc[ct][r] = 0.0f;
  }
#pragma unroll
  for (int ct = 0; ct < 4; ct++) {
    int nn = ct * 32 + m;
#pragma unroll
    for (int kc = 0; kc < 8; kc++) {
      int kg = kc * 2 + q2;
      bf16x8 b = __builtin_bit_cast(
          bf16x8, *(const short8*)(Bs + (((kg << 7) + nn) << 3)));
      acc[ct] = __builtin_amdgcn_mfma_f32_32x32x16_bf16(a[kc], b, acc[ct], 0,
                                                        0, 0);
    }
  }

  // D layout: col = lane&31, row = (reg&3) + 8*(reg>>2) + 4*(lane>>5)
#pragma unroll
  for (int r = 0; r < 16; r++) {
    int rl = (r & 3) + ((r >> 2) << 3) + (q2 << 2);
    int rg = tr + rl;
    if (rg < n) {
#pragma unroll
      for (int ct = 0; ct < 4; ct++) {
        y[(size_t)rg * FDIM + ct * 32 + m] = f2bf(acc[ct][r]);
      }
    }
  }
}

// ---------------------------------------------------------------------------
// K3: single-dispatch scan of cnt -> offs, dinv = rsqrt(degf+1), then an
// in-kernel device-wide barrier (FLAG_C), then the CSR scatter (grid-stride,
// no atomics: pos = offs[dst]+rank). csr.y stores PREMULTIPLIED w*dinv[src].
// 196 blocks x 256 (all co-resident on 256 CUs). Release/acquire flags.
// ---------------------------------------------------------------------------
__global__ __launch_bounds__(256) void scan_scatter_kernel(
    const int* __restrict__ cnt, const float* __restrict__ degf,
    int* __restrict__ part, int* __restrict__ offs, float* __restrict__ dinv,
    const int* __restrict__ ei, const float* __restrict__ ew,
    const int* __restrict__ rank, int2* __restrict__ csr) {
  __shared__ int tmp[256];
  int t = threadIdx.x;
  int bid = blockIdx.x;
  int idx = bid * 256 + t;
  int n = N_NODES;
  // dinv straight from atomically-accumulated weighted degree (+1 self loop)
  if (idx < n) dinv[idx] = rsqrtf(degf[idx] + 1.0f);
  int v = (idx < n) ? cnt[idx] : 0;
  tmp[t] = v;
  __syncthreads();
#pragma unroll
  for (int off = 1; off < 256; off <<= 1) {
    int u = (t >= off) ? tmp[t - off] : 0;
    __syncthreads();
    tmp[t] += u;
    __syncthreads();
  }
  int local_excl = tmp[t] - v;
  int block_sum = tmp[255];
  // publish block sum
  if (t == 0) {
    __hip_atomic_store(&part[bid], block_sum, __ATOMIC_RELEASE,
                       __HIP_MEMORY_SCOPE_AGENT);
    __hip_atomic_fetch_add(&part[FLAG_A], 1, __ATOMIC_ACQ_REL,
                           __HIP_MEMORY_SCOPE_AGENT);
  }
  // block 0 scans the partials once all have arrived
  if (bid == 0) {
    if (t == 0) {
      while (__hip_atomic_load(&part[FLAG_A], __ATOMIC_ACQUIRE,
                               __HIP_MEMORY_SCOPE_AGENT) < SCAN_BLOCKS) {
        __builtin_amdgcn_s_sleep(1);
      }
    }
    __syncthreads();
    __shared__ int ps[256];
    int pv = (t < SCAN_BLOCKS)
                 ? __hip_atomic_load(&part[t], __ATOMIC_RELAXED,
                                     __HIP_MEMORY_SCOPE_AGENT)
                 : 0;
    ps[t] = pv;
    __syncthreads();
#pragma unroll
    for (int off = 1; off < 256; off <<= 1) {
      int u = (t >= off) ? ps[t - off] : 0;
      __syncthreads();
      ps[t] += u;
      __syncthreads();
    }
    if (t < SCAN_BLOCKS)
      __hip_atomic_store(&part[SCANNED + t], ps[t] - pv, __ATOMIC_RELAXED,
                         __HIP_MEMORY_SCOPE_AGENT);
    __syncthreads();
    if (t == 0)
      __hip_atomic_store(&part[FLAG_B], 1, __ATOMIC_RELEASE,
                         __HIP_MEMORY_SCOPE_AGENT);
  }
  // all blocks wait for scanned offsets
  if (t == 0) {
    while (__hip_atomic_load(&part[FLAG_B], __ATOMIC_ACQUIRE,
                             __HIP_MEMORY_SCOPE_AGENT) == 0) {
      __builtin_amdgcn_s_sleep(1);
    }
  }
  __syncthreads();
  int base = __hip_atomic_load(&part[SCANNED + bid], __ATOMIC_RELAXED,
                               __HIP_MEMORY_SCOPE_AGENT);
  int excl = base + local_excl;
  if (idx < n) offs[idx] = excl;
  if (idx == n - 1) offs[n] = excl + v;

  // ---- device-wide barrier: offs[] and dinv[] complete everywhere ----
  __syncthreads();
  if (t == 0) {
    __hip_atomic_fetch_add(&part[FLAG_C], 1, __ATOMIC_ACQ_REL,
                           __HIP_MEMORY_SCOPE_AGENT);
    while (__hip_atomic_load(&part[FLAG_C], __ATOMIC_ACQUIRE,
                             __HIP_MEMORY_SCOPE_AGENT) < SCAN_BLOCKS) {
      __builtin_amdgcn_s_sleep(1);
    }
  }
  __syncthreads();

  // ---- scatter phase: grid-stride over edges ----
  for (int e = idx; e < N_EDGES; e += SCAN_BLOCKS * 256) {
    int src = ei[e];
    int dst = ei[N_EDGES + e];
    int pos = offs[dst] + rank[e];
    float wn = ew[e] * dinv[src];  // premultiply: gather loses the dinv load
    csr[pos] = make_int2(src, __float_as_int(wn));
  }
}

// ---------------------------------------------------------------------------
// K4: per-node gather (bf16 y rows) + tanh + w_lin dot + bias.
// h[dst] = tanh( dinv_d * ( dinv_d*y[dst] + sum_e (w_e*dinv_src)*y[src_e] ) )
// CSR entries are loaded COALESCED 64-wide once per wave and broadcast via
// __shfl — removes the per-edge broadcast-load latency chain; all row
// addresses are available one VALU op after a single coalesced load.
// ---------------------------------------------------------------------------
__global__ __launch_bounds__(256) void gather_kernel(
    const uint32* __restrict__ yb, const int* __restrict__ offs,
    const int2* __restrict__ csr, const float* __restrict__ dinv,
    const float* __restrict__ wl, const float* __restrict__ bl,
    float* __restrict__ out, int n) {
  int wid = (int)((blockIdx.x * (size_t)blockDim.x + threadIdx.x) >> 6);
  int lane = threadIdx.x & 63;
  if (wid >= n) return;
  float di = dinv[wid];
  uint32 uv = yb[(size_t)wid * 64 + lane];
  float ax = di * __uint_as_float(uv << 16);  // self term (one dinv_d here,
  float ay = di * __uint_as_float(uv & 0xffff0000u);  // second applied at end)
  int beg = offs[wid], end = offs[wid + 1];
  for (int base = beg; base < end; base += 64) {
    int mm = end - base;
    if (mm > 64) mm = 64;
    int2 c = make_int2(0, 0);
    if (lane < mm) c = csr[base + lane];  // one coalesced 512B load / chunk
    int j = 0;
    for (; j + 4 <= mm; j += 4) {
      int s0 = __shfl(c.x, j);
      int s1 = __shfl(c.x, j + 1);
      int s2 = __shfl(c.x, j + 2);
      int s3 = __shfl(c.x, j + 3);
      float w0 = __uint_as_float((uint32)__shfl(c.y, j));
      float w1 = __uint_as_float((uint32)__shfl(c.y, j + 1));
      float w2 = __uint_as_float((uint32)__shfl(c.y, j + 2));
      float w3 = __uint_as_float((uint32)__shfl(c.y, j + 3));
      uint32 u0 = yb[(size_t)s0 * 64 + lane];
      uint32 u1 = yb[(size_t)s1 * 64 + lane];
      uint32 u2 = yb[(size_t)s2 * 64 + lane];
      uint32 u3 = yb[(size_t)s3 * 64 + lane];
      ax += w0 * __uint_as_float(u0 << 16);
      ay += w0 * __uint_as_float(u0 & 0xffff0000u);
      ax += w1 * __uint_as_float(u1 << 16);
      ay += w1 * __uint_as_float(u1 & 0xffff0000u);
      ax += w2 * __uint_as_float(u2 << 16);
      ay += w2 * __uint_as_float(u2 & 0xffff0000u);
      ax += w3 * __uint_as_float(u3 << 16);
      ay += w3 * __uint_as_float(u3 & 0xffff0000u);
    }
    for (; j < mm; j++) {
      int s = __shfl(c.x, j);
      float wn = __uint_as_float((uint32)__shfl(c.y, j));
      uint32 u = yb[(size_t)s * 64 + lane];
      ax += wn * __uint_as_float(u << 16);
      ay += wn * __uint_as_float(u & 0xffff0000u);
    }
  }
  float2 wv = ((const float2*)wl)[lane];
  float p = tanhf(di * ax) * wv.x + tanhf(di * ay) * wv.y;
#pragma unroll
  for (int o = 32; o > 0; o >>= 1) p += __shfl_down(p, o, 64);
  if (lane == 0) out[wid] = p + bl[0];
}

// ---------------------------------------------------------------------------
extern "C" void kernel_launch(void* const* d_in, const int* in_sizes, int n_in,
                              void* d_out, int out_size, void* d_ws,
                              size_t ws_size, hipStream_t stream) {
  const float* x = (const float*)d_in[0];     // (N,128)
  const int* ei = (const int*)d_in[1];        // (2,E)
  const float* ew = (const float*)d_in[2];    // (E,)
  const float* W0 = (const float*)d_in[3];    // (128,128)
  const float* Wih = (const float*)d_in[4];   // (384,128)
  const float* Whh = (const float*)d_in[5];   // (384,128)
  const float* bih = (const float*)d_in[6];   // (384,)
  const float* bhh = (const float*)d_in[7];   // (384,)
  const float* wl = (const float*)d_in[8];    // (1,128)
  const float* bl = (const float*)d_in[9];    // (1,)
  float* out = (float*)d_out;                 // (N,1)

  // Workspace layout (all 16B-aligned)
  unsigned short* Wbf = (unsigned short*)d_ws;           // 16384 bf16 (32KB)
  unsigned short* y = Wbf + 16384;                       // N*128 bf16
  float* dinv = (float*)(y + (size_t)N_NODES * FDIM);    // 50000 f
  float* degf = dinv + N_NODES;                          // 50000 f
  int* cnt = (int*)(degf + N_NODES);                     // 50000 i
  int* rank = cnt + N_NODES;                             // 800000 i
  int* offs = rank + N_EDGES;                            // 50004 i (padded)
  int2* csr = (int2*)(offs + 50004);                     // 800000 int2
  int* part = (int*)(csr + N_EDGES);                     // 512 i

  // D1: evolve W -> bf16 frag layout + zero cnt/degf/flags
  evolve_kernel<<<FDIM, 384, 0, stream>>>(W0, Wih, Whh, bih, bhh, Wbf, cnt,
                                          degf, part);
  // D2: fused xw-MFMA (blocks 0..390) + rank histogram + weighted deg
  histxw_kernel<<<XW_BLOCKS + (N_EDGES + 255) / 256, 256, 0, stream>>>(
      ei, ew, cnt, degf, rank, x, Wbf, y, N_NODES);
  // D3: scan -> offs, dinv, device barrier, scatter to CSR (premultiplied)
  scan_scatter_kernel<<<SCAN_BLOCKS, 256, 0, stream>>>(cnt, degf, part, offs,
                                                       dinv, ei, ew, rank, csr);
  // D4: fused gather + tanh + linear
  gather_kernel<<<(N_NODES * 64) / 256, 256, 0, stream>>>(
      (const uint32*)y, offs, csr, dinv, wl, bl, out, N_NODES);
}